// Round 5
// baseline (337.190 us; speedup 1.0000x reference)
//
#include <hip/hip_runtime.h>

// ---------------------------------------------------------------------------
// SparseAttention on MI355X (gfx950)
// hidden=2048, heads=16, d=128, topk=256, N=2048, B=1
//
// Ranking path (fp32/fp64, exact):  imp[h,m] = hs[m,:] . U[:,h]
//   where U[i,h] = sum_{j in head h} Wk[i,j]*qbar[j],  qbar = mean_n(HS) @ Wq + bq
// Value path (bf16 MFMA): QKV GEMM with select-scatter epilogue (K/V write only
// the top-256 rows per head, directly into Ksel/VselT), fused attention,
// split-K O GEMM + reduce.
// ---------------------------------------------------------------------------

typedef __attribute__((ext_vector_type(8))) short bf16x8;
typedef __attribute__((ext_vector_type(4))) float f32x4;

__device__ __forceinline__ unsigned short f2bf(float x) {
    unsigned u = __float_as_uint(x);
    u += 0x7fffu + ((u >> 16) & 1u);      // round to nearest even
    return (unsigned short)(u >> 16);
}

__device__ __forceinline__ void load_lds16(const unsigned short* g, unsigned short* l) {
    __builtin_amdgcn_global_load_lds(
        (const __attribute__((address_space(1))) unsigned int*)g,
        (__attribute__((address_space(3))) unsigned int*)l,
        16, 0, 0);
}

struct Bias3 { const float* p0; const float* p1; const float* p2; };
struct Ptr4  { const float* p[4]; };

// ---------------------------------------------------------------------------
// bf16 MFMA GEMM, tile 128x128, BK=32, 256 threads (2x2 waves).
// SELECT=true (QKV): b=0 writes full bf16 C (+bq); b=1 writes only rows with
//   jpos>=0 into Ksel[h][j][d] (+bk); b=2 into VselT[h][d][j] (+bv).
// SELECT=false (O split-K): C fp32 partial = sum over K chunk b, no bias.
// ---------------------------------------------------------------------------
template <bool SELECT>
__global__ __launch_bounds__(256) void gemm_bf16(
    const unsigned short* __restrict__ A, long lda, long strideA,
    const unsigned short* __restrict__ Bt, long ldb, long strideB,
    void* __restrict__ Cv, long ldc, long strideC,
    Bias3 bias, int K,
    const int* __restrict__ jpos,
    unsigned short* __restrict__ Ksel,
    unsigned short* __restrict__ VselT)
{
    __shared__ __align__(16) unsigned short As[128][32];
    __shared__ __align__(16) unsigned short Bs[128][32];

    const int tid  = threadIdx.x;
    const int lane = tid & 63;
    const int wave = tid >> 6;
    const int wm = wave >> 1, wn = wave & 1;

    const int bm = blockIdx.y * 128;
    const int bn = blockIdx.x * 128;
    const int b  = blockIdx.z;

    const unsigned short* Ab = A  + (long)b * strideA;
    const unsigned short* Bb = Bt + (long)b * strideB;

    f32x4 acc[4][4];
#pragma unroll
    for (int i = 0; i < 4; i++)
#pragma unroll
        for (int j = 0; j < 4; j++) acc[i][j] = f32x4{0.f, 0.f, 0.f, 0.f};

    const int lr = lane >> 2;          // 0..15 row within 16-row staging group
    const int lc = (lane & 3) * 8;     // bf16 col offset (16B chunk)

    for (int k0 = 0; k0 < K; k0 += 32) {
        __syncthreads();
#pragma unroll
        for (int r0 = wave * 16; r0 < 128; r0 += 64) {
            load_lds16(Ab + (long)(bm + r0 + lr) * lda + k0 + lc, &As[r0][0]);
            load_lds16(Bb + (long)(bn + r0 + lr) * ldb + k0 + lc, &Bs[r0][0]);
        }
        __syncthreads();

        bf16x8 af[4], bf[4];
#pragma unroll
        for (int s = 0; s < 4; s++)
            af[s] = *(const bf16x8*)&As[wm * 64 + s * 16 + (lane & 15)][(lane >> 4) * 8];
#pragma unroll
        for (int t = 0; t < 4; t++)
            bf[t] = *(const bf16x8*)&Bs[wn * 64 + t * 16 + (lane & 15)][(lane >> 4) * 8];
#pragma unroll
        for (int s = 0; s < 4; s++)
#pragma unroll
            for (int t = 0; t < 4; t++)
                acc[s][t] = __builtin_amdgcn_mfma_f32_16x16x32_bf16(af[s], bf[t], acc[s][t], 0, 0, 0);
    }

    // epilogue: C/D layout col=lane&15, row=(lane>>4)*4+reg
    const float* bp = (b == 0) ? bias.p0 : (b == 1) ? bias.p1 : bias.p2;
    float* Cf = (float*)Cv;
    unsigned short* Ch = (unsigned short*)Cv;
#pragma unroll
    for (int s = 0; s < 4; s++) {
#pragma unroll
        for (int t = 0; t < 4; t++) {
            const int col  = bn + wn * 64 + t * 16 + (lane & 15);
            const int row0 = bm + wm * 64 + s * 16 + (lane >> 4) * 4;
#pragma unroll
            for (int r = 0; r < 4; r++) {
                const int row = row0 + r;
                if (SELECT) {
                    const float v = acc[s][t][r] + bp[col];
                    if (b == 0) {
                        Ch[(long)row * ldc + col] = f2bf(v);
                    } else {
                        const int hh = col >> 7, dd = col & 127;
                        const int j = jpos[hh * 2048 + row];
                        if (j >= 0) {
                            if (b == 1) Ksel [hh * 32768 + j * 128 + dd]  = f2bf(v);
                            else        VselT[hh * 32768 + dd * 256 + j]  = f2bf(v);
                        }
                    }
                } else {
                    Cf[(long)b * strideC + (long)row * ldc + col] = acc[s][t][r];
                }
            }
        }
    }
}

// out = partial0 + partial1 + bo  (fp32, vectorized)
__global__ __launch_bounds__(256) void oreduce(const float* __restrict__ part,
                                               const float* __restrict__ bo,
                                               float* __restrict__ out) {
    const long i = ((long)blockIdx.x * 256 + threadIdx.x) * 4;
    float4 a = *(const float4*)(part + i);
    float4 b = *(const float4*)(part + 4194304 + i);
    const int col = (int)(i & 2047);
    float4 o;
    o.x = a.x + b.x + bo[col];
    o.y = a.y + b.y + bo[col + 1];
    o.z = a.z + b.z + bo[col + 2];
    o.w = a.w + b.w + bo[col + 3];
    *(float4*)(out + i) = o;
}

// ---------------------------------------------------------------------------
// Fused attention, 64-query tiles: S = scale*Q Ksel^T (fp32 regs),
// in-wave softmax, P(bf16)->LDS, O = P Vsel * (1/l), write to Att.
// ---------------------------------------------------------------------------
__global__ __launch_bounds__(256, 2) void attn_kernel(
    const unsigned short* __restrict__ Qb,     // [2048][2048] (token, h*128+d)
    const unsigned short* __restrict__ Ksel,   // [16][256][128]
    const unsigned short* __restrict__ VselT,  // [16][128][256]
    unsigned short* __restrict__ Att)          // [2048][2048]
{
    __shared__ __align__(16) unsigned short Qs[64][32];     //  4 KB
    __shared__ __align__(16) unsigned short Ks[256][32];    // 16 KB
    __shared__ __align__(16) unsigned short Vs[128][32];    //  8 KB
    __shared__ __align__(16) unsigned short Ps[64][264];    // 33 KB (pad 8)
    __shared__ float linv[64];

    const int tid  = threadIdx.x;
    const int lane = tid & 63;
    const int wave = tid >> 6;
    const int bm = blockIdx.x * 64;
    const int h  = blockIdx.y;
    const int lr = lane >> 2, lc = (lane & 3) * 8;

    const unsigned short* Kh = Ksel  + h * 32768;
    const unsigned short* Vh = VselT + h * 32768;

    // ---- phase 1: S tile 64x256, wave owns rows [wave*16, +16)
    f32x4 acc[16];
#pragma unroll
    for (int t = 0; t < 16; t++) acc[t] = f32x4{0.f, 0.f, 0.f, 0.f};

    for (int k0 = 0; k0 < 128; k0 += 32) {
        __syncthreads();
        load_lds16(Qb + (long)(bm + wave * 16 + lr) * 2048 + h * 128 + k0 + lc,
                   &Qs[wave * 16][0]);
#pragma unroll
        for (int q = 0; q < 4; q++)
            load_lds16(Kh + (wave * 64 + q * 16 + lr) * 128 + k0 + lc,
                       &Ks[wave * 64 + q * 16][0]);
        __syncthreads();

        bf16x8 af = *(const bf16x8*)&Qs[wave * 16 + (lane & 15)][(lane >> 4) * 8];
#pragma unroll
        for (int t = 0; t < 16; t++) {
            bf16x8 bfv = *(const bf16x8*)&Ks[t * 16 + (lane & 15)][(lane >> 4) * 8];
            acc[t] = __builtin_amdgcn_mfma_f32_16x16x32_bf16(af, bfv, acc[t], 0, 0, 0);
        }
    }

    // ---- phase 2: in-wave softmax over 256 cols; P = exp(scale*(s-max)), bf16
    const float se = 0.08838834764831845f * 1.4426950408889634f;  // scale*log2(e)
#pragma unroll
    for (int r = 0; r < 4; r++) {
        float mx = -3.0e38f;
#pragma unroll
        for (int t = 0; t < 16; t++) mx = fmaxf(mx, acc[t][r]);
#pragma unroll
        for (int off = 1; off < 16; off <<= 1) mx = fmaxf(mx, __shfl_xor(mx, off));
        float sum = 0.f;
#pragma unroll
        for (int t = 0; t < 16; t++) {
            float p = exp2f((acc[t][r] - mx) * se);
            acc[t][r] = p;
            sum += p;
        }
#pragma unroll
        for (int off = 1; off < 16; off <<= 1) sum += __shfl_xor(sum, off);
        const int row = wave * 16 + (lane >> 4) * 4 + r;
#pragma unroll
        for (int t = 0; t < 16; t++)
            Ps[row][t * 16 + (lane & 15)] = f2bf(acc[t][r]);
        if ((lane & 15) == 0) linv[row] = 1.0f / sum;
    }

    // ---- phase 3: O = P @ Vsel, 2x2 waves over 64x128
    const int wm2 = wave >> 1, wn2 = wave & 1;
    f32x4 acc2[2][4];
#pragma unroll
    for (int i = 0; i < 2; i++)
#pragma unroll
        for (int j = 0; j < 4; j++) acc2[i][j] = f32x4{0.f, 0.f, 0.f, 0.f};

    for (int j0 = 0; j0 < 256; j0 += 32) {
        __syncthreads();   // (also makes Ps/linv visible on first iteration)
#pragma unroll
        for (int q = 0; q < 2; q++)
            load_lds16(Vh + (wave * 32 + q * 16 + lr) * 256 + j0 + lc,
                       &Vs[wave * 32 + q * 16][0]);
        __syncthreads();

        bf16x8 af2[2], bf2v[4];
#pragma unroll
        for (int s2 = 0; s2 < 2; s2++)
            af2[s2] = *(const bf16x8*)&Ps[wm2 * 32 + s2 * 16 + (lane & 15)][j0 + (lane >> 4) * 8];
#pragma unroll
        for (int t2 = 0; t2 < 4; t2++)
            bf2v[t2] = *(const bf16x8*)&Vs[wn2 * 64 + t2 * 16 + (lane & 15)][(lane >> 4) * 8];
#pragma unroll
        for (int s2 = 0; s2 < 2; s2++)
#pragma unroll
            for (int t2 = 0; t2 < 4; t2++)
                acc2[s2][t2] = __builtin_amdgcn_mfma_f32_16x16x32_bf16(af2[s2], bf2v[t2], acc2[s2][t2], 0, 0, 0);
    }

    // ---- epilogue: divide by row sum, write Att[token][h*128+d]
#pragma unroll
    for (int s2 = 0; s2 < 2; s2++) {
#pragma unroll
        for (int t2 = 0; t2 < 4; t2++) {
            const int d = wn2 * 64 + t2 * 16 + (lane & 15);
#pragma unroll
            for (int r = 0; r < 4; r++) {
                const int row = wm2 * 32 + s2 * 16 + (lane >> 4) * 4 + r;
                float v = acc2[s2][t2][r] * linv[row];
                Att[(long)(bm + row) * 2048 + h * 128 + d] = f2bf(v);
            }
        }
    }
}

// ---------------------------------------------------------------------------
// prep: blocks [0,16384): fp32->bf16 transposed weights (4 matrices);
//       blocks [16384,16896): colsum partials of hs (ranking stage 1)
// ---------------------------------------------------------------------------
__global__ __launch_bounds__(256) void prep_kernel(Ptr4 srcs, unsigned short* __restrict__ WT4,
                                                   const float* __restrict__ hs,
                                                   double* __restrict__ part) {
    const int b = blockIdx.x;
    const int tid = threadIdx.x;
    if (b < 16384) {
        __shared__ float tile[32][33];
        const int z = b >> 12, xy = b & 4095;
        const float* W = srcs.p[z];
        unsigned short* WT = WT4 + (long)z * 4194304;
        const int bx = (xy & 63) * 32;   // n
        const int by = (xy >> 6) * 32;   // k
        const int x = tid & 31, y = tid >> 5;   // y in 0..7
#pragma unroll
        for (int i = 0; i < 32; i += 8)
            tile[y + i][x] = W[(long)(by + y + i) * 2048 + bx + x];
        __syncthreads();
#pragma unroll
        for (int i = 0; i < 32; i += 8)
            WT[(long)(bx + y + i) * 2048 + by + x] = f2bf(tile[x][y + i]);
    } else {
        const int c = b - 16384;                 // 0..511
        const int col = (c & 7) * 256 + tid;
        const int r0  = (c >> 3) * 32;
        double a = 0.0;
#pragma unroll 4
        for (int r = 0; r < 32; r++) a += (double)hs[(long)(r0 + r) * 2048 + col];
        part[(long)(c >> 3) * 2048 + col] = a;
    }
}

__global__ void fill_kernel(float* p, float v, long n) {
    long i = ((long)blockIdx.x * blockDim.x + threadIdx.x) * 4;
    if (i + 3 < n) { p[i] = v; p[i+1] = v; p[i+2] = v; p[i+3] = v; }
}

// ---------------------------------------------------------------------------
// Ranking path
// ---------------------------------------------------------------------------
__global__ __launch_bounds__(256) void mean_qsum_part(const double* __restrict__ part,
                                                      const float* __restrict__ Wq,
                                                      double* __restrict__ partq) {
    __shared__ float hsb[32];
    const int j  = blockIdx.x * 256 + threadIdx.x;
    const int i0 = blockIdx.y * 32;
    if (threadIdx.x < 32) {
        double s = 0.0;
#pragma unroll 4
        for (int g = 0; g < 64; g++) s += part[(long)g * 2048 + i0 + threadIdx.x];
        hsb[threadIdx.x] = (float)(s * (1.0 / 2048.0));
    }
    __syncthreads();
    double a = 0.0;
#pragma unroll 4
    for (int r = 0; r < 32; r++)
        a += (double)hsb[r] * (double)Wq[(long)(i0 + r) * 2048 + j];
    partq[(long)blockIdx.y * 2048 + j] = a;
}

__global__ void qsum_fin(const double* __restrict__ partq, const float* __restrict__ bq,
                         float* __restrict__ qbar) {
    const int j = blockIdx.x * 64 + threadIdx.x;
    double s = (double)bq[j];
#pragma unroll 4
    for (int g = 0; g < 64; g++) s += partq[(long)g * 2048 + j];
    qbar[j] = (float)s;
}

__global__ __launch_bounds__(256) void u_kernel(const float* __restrict__ Wk,
                                                const float* __restrict__ qbar,
                                                float* __restrict__ U) {
    const int i = blockIdx.x, t = threadIdx.x;
#pragma unroll
    for (int r = 0; r < 2; r++) {
        const int e = r * 1024 + t * 4;
        float4 w = *(const float4*)(Wk + (long)i * 2048 + e);
        float4 q = *(const float4*)(qbar + e);
        float a = w.x * q.x + w.y * q.y + w.z * q.z + w.w * q.w;
#pragma unroll
        for (int off = 16; off; off >>= 1) a += __shfl_xor(a, off);
        if ((t & 31) == 0) U[(long)i * 16 + r * 8 + (t >> 5)] = a;
    }
}

// fused: HSb = bf16(hs row)  AND  imp[h,m] = hs[m,:] . U[:,h]
__global__ __launch_bounds__(256) void cast_imp_kernel(const float* __restrict__ hs,
                                                       const float* __restrict__ U,
                                                       unsigned short* __restrict__ HSb,
                                                       float* __restrict__ imp) {
    __shared__ float row[2048];
    __shared__ float red[4][16];
    const int m = blockIdx.x, t = threadIdx.x;
    for (int i = t; i < 2048; i += 256) {
        float v = hs[(long)m * 2048 + i];
        row[i] = v;
        HSb[(long)m * 2048 + i] = f2bf(v);
    }
    __syncthreads();
    float p[16];
#pragma unroll
    for (int h = 0; h < 16; h++) p[h] = 0.f;
    for (int i = t * 8; i < t * 8 + 8; i++) {
        const float v = row[i];
        const float* u = U + i * 16;
#pragma unroll
        for (int h = 0; h < 16; h++) p[h] += v * u[h];
    }
#pragma unroll
    for (int off = 32; off; off >>= 1)
#pragma unroll
        for (int h = 0; h < 16; h++) p[h] += __shfl_down(p[h], off);
    if ((t & 63) == 0)
#pragma unroll
        for (int h = 0; h < 16; h++) red[t >> 6][h] = p[h];
    __syncthreads();
    if (t < 16)
        imp[(long)t * 2048 + m] = red[0][t] + red[1][t] + red[2][t] + red[3][t];
}

// ---------------------------------------------------------------------------
// exact top-256 per head, emitting inverse map jpos[h][token] = j (or -1).
// One wave per head; register-resident ballot binary search; strictly-greater
// elements ranked first (stable r asc, lane asc), then threshold ties
// lowest-index-first until 256.
// ---------------------------------------------------------------------------
__global__ __launch_bounds__(64) void topk_jpos(const float* __restrict__ imp,
                                                int* __restrict__ jpos) {
    const int h = blockIdx.x;
    const int lane = threadIdx.x;
    unsigned u[32];
#pragma unroll
    for (int r = 0; r < 32; r++) {
        unsigned x = __float_as_uint(imp[(long)h * 2048 + r * 64 + lane]);
        u[r] = (x & 0x80000000u) ? ~x : (x | 0x80000000u);
    }
    unsigned cur = 0;
    for (int b = 31; b >= 0; b--) {
        const unsigned cand = cur | (1u << b);
        int tot = 0;
#pragma unroll
        for (int r = 0; r < 32; r++)
            tot += (int)__popcll(__ballot(u[r] >= cand));
        if (tot >= 256) cur = cand;
    }
    const unsigned long long below = (1ull << lane) - 1ull;
    int pos[32];
    int base = 0;
#pragma unroll
    for (int r = 0; r < 32; r++) {
        const bool q = u[r] > cur;
        const unsigned long long m = __ballot(q);
        pos[r] = q ? base + (int)__popcll(m & below) : -1;
        base += (int)__popcll(m);
    }
    // ties at threshold continue from the strict count
#pragma unroll
    for (int r = 0; r < 32; r++) {
        const bool q = (u[r] == cur);
        const unsigned long long m = __ballot(q);
        if (q) {
            const int p = base + (int)__popcll(m & below);
            pos[r] = (p < 256) ? p : -1;
        }
        base += (int)__popcll(m);
    }
#pragma unroll
    for (int r = 0; r < 32; r++)
        jpos[h * 2048 + r * 64 + lane] = pos[r];
}

// ---------------------------------------------------------------------------
extern "C" void kernel_launch(void* const* d_in, const int* in_sizes, int n_in,
                              void* d_out, int out_size, void* d_ws, size_t ws_size,
                              hipStream_t stream)
{
    const float* hs = (const float*)d_in[0];
    const float* Wq = (const float*)d_in[1];
    const float* bq = (const float*)d_in[2];
    const float* Wk = (const float*)d_in[3];
    const float* bk = (const float*)d_in[4];
    const float* Wv = (const float*)d_in[5];
    const float* bv = (const float*)d_in[6];
    const float* Wo = (const float*)d_in[7];
    const float* bo = (const float*)d_in[8];

    char* ws = (char*)d_ws;
    size_t off = 0;
    auto alloc = [&](size_t b) -> void* {
        void* p = ws + off;
        off = (off + b + 255) & ~(size_t)255;
        return p;
    };
    unsigned short* HSb   = (unsigned short*)alloc(8388608);     // 2048x2048 bf16
    unsigned short* WT4   = (unsigned short*)alloc(4 * 8388608); // WqT|WkT|WvT|WoT
    unsigned short* Qb    = (unsigned short*)alloc(8388608);     // Q [2048][2048]
    unsigned short* Att   = (unsigned short*)alloc(8388608);
    unsigned short* Ksel  = (unsigned short*)alloc(1048576);     // [16][256][128]
    unsigned short* VselT = (unsigned short*)alloc(1048576);     // [16][128][256]
    float* Opart = (float*)alloc(2 * 16777216);                  // [2][2048][2048] fp32
    double* part  = (double*)alloc(1048576);                     // [64][2048]
    double* partq = (double*)alloc(1048576);                     // [64][2048]
    float* qbar  = (float*)alloc(8192);
    float* U     = (float*)alloc(131072);                        // [2048][16]
    float* imp   = (float*)alloc(131072);                        // [16][2048]
    int*   jpos  = (int*)alloc(131072);                          // [16][2048]

    if (off > ws_size) {
        fill_kernel<<<4096, 256, 0, stream>>>((float*)d_out, 12345.0f, (long)out_size);
        return;
    }

    unsigned short* WoT = WT4 + 3 * 4194304;

    // 1. weight transposes + colsum partials (fused, independent roles)
    prep_kernel<<<16896, 256, 0, stream>>>(Ptr4{{Wq, Wk, Wv, Wo}}, WT4, hs, part);

    // 2-5. ranking chain (exact, deterministic)
    mean_qsum_part<<<dim3(8, 64), 256, 0, stream>>>(part, Wq, partq);
    qsum_fin<<<32, 64, 0, stream>>>(partq, bq, qbar);
    u_kernel<<<2048, 256, 0, stream>>>(Wk, qbar, U);
    cast_imp_kernel<<<2048, 256, 0, stream>>>(hs, U, HSb, imp);

    // 6. top-256 per head -> inverse map jpos[h][token]
    topk_jpos<<<16, 64, 0, stream>>>(imp, jpos);

    // 7. QKV batched GEMM; K/V epilogues scatter selected rows only
    gemm_bf16<true><<<dim3(16, 16, 3), 256, 0, stream>>>(
        HSb, 2048, 0, WT4, 2048, 4194304, Qb, 2048, 0,
        Bias3{bq, bk, bv}, 2048, jpos, Ksel, VselT);

    // 8. fused attention: S, softmax, PV  (64-query tiles)
    attn_kernel<<<dim3(32, 16), 256, 0, stream>>>(Qb, Ksel, VselT, Att);

    // 9. O GEMM split-K=2: fp32 partials (K chunks of 1024)
    gemm_bf16<false><<<dim3(16, 16, 2), 256, 0, stream>>>(
        Att, 2048, 1024, WoT, 2048, 1024, Opart, 2048, 4194304,
        Bias3{nullptr, nullptr, nullptr}, 1024, nullptr, nullptr, nullptr);

    // 10. out = Opart0 + Opart1 + bo
    oreduce<<<4096, 256, 0, stream>>>(Opart, bo, (float*)d_out);
}

// Round 6
// 327.030 us; speedup vs baseline: 1.0311x; 1.0311x over previous
//
#include <hip/hip_runtime.h>

// ---------------------------------------------------------------------------
// SparseAttention on MI355X (gfx950)
// hidden=2048, heads=16, d=128, topk=256, N=2048, B=1
//
// Ranking path (fp32/fp64, exact):  imp[h,m] = hs[m,:] . U[:,h]
//   where U[i,h] = sum_{j in head h} Wk[i,j]*qbar[j],  qbar = mean_n(HS) @ Wq + bq
// Value path (bf16 MFMA): QKV GEMM with select-scatter epilogue (K/V write only
// the top-256 rows per head, directly into Ksel/VselT), fused attention,
// split-K O GEMM + reduce.
// ---------------------------------------------------------------------------

typedef __attribute__((ext_vector_type(8))) short bf16x8;
typedef __attribute__((ext_vector_type(4))) float f32x4;

__device__ __forceinline__ unsigned short f2bf(float x) {
    unsigned u = __float_as_uint(x);
    u += 0x7fffu + ((u >> 16) & 1u);      // round to nearest even
    return (unsigned short)(u >> 16);
}

__device__ __forceinline__ void load_lds16(const unsigned short* g, unsigned short* l) {
    __builtin_amdgcn_global_load_lds(
        (const __attribute__((address_space(1))) unsigned int*)g,
        (__attribute__((address_space(3))) unsigned int*)l,
        16, 0, 0);
}

struct Bias3 { const float* p0; const float* p1; const float* p2; };
struct Ptr4  { const float* p[4]; };

// ---------------------------------------------------------------------------
// bf16 MFMA GEMM, tile 128x128, BK=32, 256 threads (2x2 waves).
// SELECT=true (QKV): b=0 writes full bf16 C (+bq); b=1 writes only rows with
//   jpos>=0 into Ksel[h][j][d] (+bk); b=2 into VselT[h][d][j] (+bv).
//   NOTE: head index hh = bn>>7 is block-uniform; jpos loads hoisted (16/lane).
// SELECT=false (O split-K): C fp32 partial = sum over K chunk b, no bias.
// ---------------------------------------------------------------------------
template <bool SELECT>
__global__ __launch_bounds__(256) void gemm_bf16(
    const unsigned short* __restrict__ A, long lda, long strideA,
    const unsigned short* __restrict__ Bt, long ldb, long strideB,
    void* __restrict__ Cv, long ldc, long strideC,
    Bias3 bias, int K,
    const int* __restrict__ jpos,
    unsigned short* __restrict__ Ksel,
    unsigned short* __restrict__ VselT)
{
    __shared__ __align__(16) unsigned short As[128][32];
    __shared__ __align__(16) unsigned short Bs[128][32];

    const int tid  = threadIdx.x;
    const int lane = tid & 63;
    const int wave = tid >> 6;
    const int wm = wave >> 1, wn = wave & 1;

    const int bm = blockIdx.y * 128;
    const int bn = blockIdx.x * 128;
    const int b  = blockIdx.z;

    const unsigned short* Ab = A  + (long)b * strideA;
    const unsigned short* Bb = Bt + (long)b * strideB;

    f32x4 acc[4][4];
#pragma unroll
    for (int i = 0; i < 4; i++)
#pragma unroll
        for (int j = 0; j < 4; j++) acc[i][j] = f32x4{0.f, 0.f, 0.f, 0.f};

    const int lr = lane >> 2;          // 0..15 row within 16-row staging group
    const int lc = (lane & 3) * 8;     // bf16 col offset (16B chunk)

    for (int k0 = 0; k0 < K; k0 += 32) {
        __syncthreads();
#pragma unroll
        for (int r0 = wave * 16; r0 < 128; r0 += 64) {
            load_lds16(Ab + (long)(bm + r0 + lr) * lda + k0 + lc, &As[r0][0]);
            load_lds16(Bb + (long)(bn + r0 + lr) * ldb + k0 + lc, &Bs[r0][0]);
        }
        __syncthreads();

        bf16x8 af[4], bf[4];
#pragma unroll
        for (int s = 0; s < 4; s++)
            af[s] = *(const bf16x8*)&As[wm * 64 + s * 16 + (lane & 15)][(lane >> 4) * 8];
#pragma unroll
        for (int t = 0; t < 4; t++)
            bf[t] = *(const bf16x8*)&Bs[wn * 64 + t * 16 + (lane & 15)][(lane >> 4) * 8];
#pragma unroll
        for (int s = 0; s < 4; s++)
#pragma unroll
            for (int t = 0; t < 4; t++)
                acc[s][t] = __builtin_amdgcn_mfma_f32_16x16x32_bf16(af[s], bf[t], acc[s][t], 0, 0, 0);
    }

    // epilogue: C/D layout col=lane&15, row=(lane>>4)*4+reg
    const float* bp = (b == 0) ? bias.p0 : (b == 1) ? bias.p1 : bias.p2;
    float* Cf = (float*)Cv;
    unsigned short* Ch = (unsigned short*)Cv;

    if (SELECT && b != 0) {
        // hoisted selection map: head is block-uniform, rows are t-independent
        const int hh = bn >> 7;
        int jv[4][4];
#pragma unroll
        for (int s = 0; s < 4; s++)
#pragma unroll
            for (int r = 0; r < 4; r++)
                jv[s][r] = jpos[hh * 2048 + bm + wm * 64 + s * 16 + (lane >> 4) * 4 + r];
#pragma unroll
        for (int s = 0; s < 4; s++) {
#pragma unroll
            for (int t = 0; t < 4; t++) {
                const int col = bn + wn * 64 + t * 16 + (lane & 15);
                const int dd  = col & 127;
                const float bv = bp[col];
#pragma unroll
                for (int r = 0; r < 4; r++) {
                    const int j = jv[s][r];
                    if (j >= 0) {
                        const unsigned short h16 = f2bf(acc[s][t][r] + bv);
                        if (b == 1) Ksel [hh * 32768 + j * 128 + dd] = h16;
                        else        VselT[hh * 32768 + dd * 256 + j] = h16;
                    }
                }
            }
        }
    } else {
#pragma unroll
        for (int s = 0; s < 4; s++) {
#pragma unroll
            for (int t = 0; t < 4; t++) {
                const int col  = bn + wn * 64 + t * 16 + (lane & 15);
                const int row0 = bm + wm * 64 + s * 16 + (lane >> 4) * 4;
#pragma unroll
                for (int r = 0; r < 4; r++) {
                    const int row = row0 + r;
                    if (SELECT) Ch[(long)row * ldc + col] = f2bf(acc[s][t][r] + bp[col]);
                    else        Cf[(long)b * strideC + (long)row * ldc + col] = acc[s][t][r];
                }
            }
        }
    }
}

// out = partial0 + partial1 + bo  (fp32, vectorized)
__global__ __launch_bounds__(256) void oreduce(const float* __restrict__ part,
                                               const float* __restrict__ bo,
                                               float* __restrict__ out) {
    const long i = ((long)blockIdx.x * 256 + threadIdx.x) * 4;
    float4 a = *(const float4*)(part + i);
    float4 b = *(const float4*)(part + 4194304 + i);
    const int col = (int)(i & 2047);
    float4 o;
    o.x = a.x + b.x + bo[col];
    o.y = a.y + b.y + bo[col + 1];
    o.z = a.z + b.z + bo[col + 2];
    o.w = a.w + b.w + bo[col + 3];
    *(float4*)(out + i) = o;
}

// ---------------------------------------------------------------------------
// Fused attention, 64-query tiles: S = scale*Q Ksel^T (fp32 regs),
// in-wave softmax, P(bf16)->LDS, O = P Vsel * (1/l), write to Att.
// Flat smem overlay (50 KB): phase1 {Qs[2][64][32], Ks[2][256][32]} is reused
// after a drain barrier by {Ps[64][264], Vs[2][128][32]}. Two 32-wide chunks
// staged per barrier pair.
// ---------------------------------------------------------------------------
#define QS_OFF(c)  ((c) * 2048)
#define KS_OFF(c)  (4096 + (c) * 8192)
#define PS_OFF     0
#define VS_OFF(c)  (16896 + (c) * 4096)

__global__ __launch_bounds__(256, 2) void attn_kernel(
    const unsigned short* __restrict__ Qb,     // [2048][2048] (token, h*128+d)
    const unsigned short* __restrict__ Ksel,   // [16][256][128]
    const unsigned short* __restrict__ VselT,  // [16][128][256]
    unsigned short* __restrict__ Att)          // [2048][2048]
{
    __shared__ __align__(16) unsigned short smem[25088];   // 50176 B
    __shared__ float linv[64];

    const int tid  = threadIdx.x;
    const int lane = tid & 63;
    const int wave = tid >> 6;
    const int bm = blockIdx.x * 64;
    const int h  = blockIdx.y;
    const int lr = lane >> 2, lc = (lane & 3) * 8;

    const unsigned short* Kh = Ksel  + h * 32768;
    const unsigned short* Vh = VselT + h * 32768;

    // ---- phase 1: S tile 64x256, wave owns rows [wave*16, +16)
    f32x4 acc[16];
#pragma unroll
    for (int t = 0; t < 16; t++) acc[t] = f32x4{0.f, 0.f, 0.f, 0.f};

#pragma unroll
    for (int c2 = 0; c2 < 2; c2++) {           // d-chunks of 64
        __syncthreads();
#pragma unroll
        for (int c = 0; c < 2; c++) {          // 32-wide sub-chunks
            const int k0 = c2 * 64 + c * 32;
            // Q: 64 rows, 1 wave-load per wave (16 rows each)
            load_lds16(Qb + (long)(bm + wave * 16 + lr) * 2048 + h * 128 + k0 + lc,
                       &smem[QS_OFF(c) + wave * 512]);
            // K: 256 rows, 4 wave-loads per wave
#pragma unroll
            for (int q = 0; q < 4; q++)
                load_lds16(Kh + (wave * 64 + q * 16 + lr) * 128 + k0 + lc,
                           &smem[KS_OFF(c) + (wave * 64 + q * 16) * 32]);
        }
        __syncthreads();
#pragma unroll
        for (int kk = 0; kk < 2; kk++) {
            bf16x8 af = *(const bf16x8*)&smem[QS_OFF(kk) + (wave * 16 + (lane & 15)) * 32 + (lane >> 4) * 8];
#pragma unroll
            for (int t = 0; t < 16; t++) {
                bf16x8 bfv = *(const bf16x8*)&smem[KS_OFF(kk) + (t * 16 + (lane & 15)) * 32 + (lane >> 4) * 8];
                acc[t] = __builtin_amdgcn_mfma_f32_16x16x32_bf16(af, bfv, acc[t], 0, 0, 0);
            }
        }
    }
    __syncthreads();   // all Q/K frag reads done -> region reusable for Ps/Vs

    // ---- phase 2: in-wave softmax over 256 cols; P = exp(scale*(s-max)), bf16
    const float se = 0.08838834764831845f * 1.4426950408889634f;  // scale*log2(e)
#pragma unroll
    for (int r = 0; r < 4; r++) {
        float mx = -3.0e38f;
#pragma unroll
        for (int t = 0; t < 16; t++) mx = fmaxf(mx, acc[t][r]);
#pragma unroll
        for (int off = 1; off < 16; off <<= 1) mx = fmaxf(mx, __shfl_xor(mx, off));
        float sum = 0.f;
#pragma unroll
        for (int t = 0; t < 16; t++) {
            float p = exp2f((acc[t][r] - mx) * se);
            acc[t][r] = p;
            sum += p;
        }
#pragma unroll
        for (int off = 1; off < 16; off <<= 1) sum += __shfl_xor(sum, off);
        const int row = wave * 16 + (lane >> 4) * 4 + r;
#pragma unroll
        for (int t = 0; t < 16; t++)
            smem[PS_OFF + row * 264 + t * 16 + (lane & 15)] = f2bf(acc[t][r]);
        if ((lane & 15) == 0) linv[row] = 1.0f / sum;
    }

    // ---- phase 3: O = P @ Vsel, 2x2 waves over 64x128; stage 2 V chunks/iter
    const int wm2 = wave >> 1, wn2 = wave & 1;
    f32x4 acc2[2][4];
#pragma unroll
    for (int i = 0; i < 2; i++)
#pragma unroll
        for (int j = 0; j < 4; j++) acc2[i][j] = f32x4{0.f, 0.f, 0.f, 0.f};

#pragma unroll
    for (int c2 = 0; c2 < 4; c2++) {           // j-chunks of 64
        // stage Vs chunks (region disjoint from Ps; phase1 drained by barrier above)
#pragma unroll
        for (int c = 0; c < 2; c++) {
            const int j0 = c2 * 64 + c * 32;
#pragma unroll
            for (int q = 0; q < 2; q++)
                load_lds16(Vh + (wave * 32 + q * 16 + lr) * 256 + j0 + lc,
                           &smem[VS_OFF(c) + (wave * 32 + q * 16) * 32]);
        }
        __syncthreads();   // staged V + (first iter) Ps visible
#pragma unroll
        for (int c = 0; c < 2; c++) {
            const int j0 = c2 * 64 + c * 32;
            bf16x8 af2[2], bf2v[4];
#pragma unroll
            for (int s2 = 0; s2 < 2; s2++)
                af2[s2] = *(const bf16x8*)&smem[PS_OFF + (wm2 * 32 + s2 * 16 + (lane & 15)) * 264 + j0 + (lane >> 4) * 8];
#pragma unroll
            for (int t2 = 0; t2 < 4; t2++)
                bf2v[t2] = *(const bf16x8*)&smem[VS_OFF(c) + (wn2 * 64 + t2 * 16 + (lane & 15)) * 32 + (lane >> 4) * 8];
#pragma unroll
            for (int s2 = 0; s2 < 2; s2++)
#pragma unroll
                for (int t2 = 0; t2 < 4; t2++)
                    acc2[s2][t2] = __builtin_amdgcn_mfma_f32_16x16x32_bf16(af2[s2], bf2v[t2], acc2[s2][t2], 0, 0, 0);
        }
        __syncthreads();   // V frag reads done before next stage overwrites
    }

    // ---- epilogue: divide by row sum, write Att[token][h*128+d]
#pragma unroll
    for (int s2 = 0; s2 < 2; s2++) {
#pragma unroll
        for (int t2 = 0; t2 < 4; t2++) {
            const int d = wn2 * 64 + t2 * 16 + (lane & 15);
#pragma unroll
            for (int r = 0; r < 4; r++) {
                const int row = wm2 * 32 + s2 * 16 + (lane >> 4) * 4 + r;
                float v = acc2[s2][t2][r] * linv[row];
                Att[(long)(bm + row) * 2048 + h * 128 + d] = f2bf(v);
            }
        }
    }
}

// ---------------------------------------------------------------------------
// prep: blocks [0,4096): fp32->bf16 transposed weights, 64x64 tiles (4 mats);
//       blocks [4096,4608): colsum partials of hs (ranking stage 1)
// ---------------------------------------------------------------------------
__global__ __launch_bounds__(256) void prep_kernel(Ptr4 srcs, unsigned short* __restrict__ WT4,
                                                   const float* __restrict__ hs,
                                                   double* __restrict__ part) {
    const int b = blockIdx.x;
    const int tid = threadIdx.x;
    if (b < 4096) {
        __shared__ float tile[64][65];
        const int z = b >> 10, xy = b & 1023;
        const float* W = srcs.p[z];
        unsigned short* WT = WT4 + (long)z * 4194304;
        const int bx = (xy & 31) * 64;   // n
        const int by = (xy >> 5) * 64;   // k
        const int x = tid & 63, y = tid >> 6;   // y in 0..3
#pragma unroll
        for (int i = 0; i < 64; i += 4)
            tile[y + i][x] = W[(long)(by + y + i) * 2048 + bx + x];
        __syncthreads();
#pragma unroll
        for (int i = 0; i < 64; i += 4)
            WT[(long)(bx + y + i) * 2048 + by + x] = f2bf(tile[x][y + i]);
    } else {
        const int c = b - 4096;                  // 0..511
        const int col = (c & 7) * 256 + tid;
        const int r0  = (c >> 3) * 32;
        double a = 0.0;
#pragma unroll 4
        for (int r = 0; r < 32; r++) a += (double)hs[(long)(r0 + r) * 2048 + col];
        part[(long)(c >> 3) * 2048 + col] = a;
    }
}

__global__ void fill_kernel(float* p, float v, long n) {
    long i = ((long)blockIdx.x * blockDim.x + threadIdx.x) * 4;
    if (i + 3 < n) { p[i] = v; p[i+1] = v; p[i+2] = v; p[i+3] = v; }
}

// ---------------------------------------------------------------------------
// Ranking path
// ---------------------------------------------------------------------------
__global__ __launch_bounds__(256) void mean_qsum_part(const double* __restrict__ part,
                                                      const float* __restrict__ Wq,
                                                      double* __restrict__ partq) {
    __shared__ float hsb[32];
    const int j  = blockIdx.x * 256 + threadIdx.x;
    const int i0 = blockIdx.y * 32;
    if (threadIdx.x < 32) {
        double s = 0.0;
#pragma unroll 4
        for (int g = 0; g < 64; g++) s += part[(long)g * 2048 + i0 + threadIdx.x];
        hsb[threadIdx.x] = (float)(s * (1.0 / 2048.0));
    }
    __syncthreads();
    double a = 0.0;
#pragma unroll 4
    for (int r = 0; r < 32; r++)
        a += (double)hsb[r] * (double)Wq[(long)(i0 + r) * 2048 + j];
    partq[(long)blockIdx.y * 2048 + j] = a;
}

__global__ void qsum_fin(const double* __restrict__ partq, const float* __restrict__ bq,
                         float* __restrict__ qbar) {
    const int j = blockIdx.x * 64 + threadIdx.x;
    double s = (double)bq[j];
#pragma unroll 4
    for (int g = 0; g < 64; g++) s += partq[(long)g * 2048 + j];
    qbar[j] = (float)s;
}

__global__ __launch_bounds__(256) void u_kernel(const float* __restrict__ Wk,
                                                const float* __restrict__ qbar,
                                                float* __restrict__ U) {
    const int i = blockIdx.x, t = threadIdx.x;
#pragma unroll
    for (int r = 0; r < 2; r++) {
        const int e = r * 1024 + t * 4;
        float4 w = *(const float4*)(Wk + (long)i * 2048 + e);
        float4 q = *(const float4*)(qbar + e);
        float a = w.x * q.x + w.y * q.y + w.z * q.z + w.w * q.w;
#pragma unroll
        for (int off = 16; off; off >>= 1) a += __shfl_xor(a, off);
        if ((t & 31) == 0) U[(long)i * 16 + r * 8 + (t >> 5)] = a;
    }
}

// fused: HSb = bf16(hs row)  AND  imp[h,m] = hs[m,:] . U[:,h]
__global__ __launch_bounds__(256) void cast_imp_kernel(const float* __restrict__ hs,
                                                       const float* __restrict__ U,
                                                       unsigned short* __restrict__ HSb,
                                                       float* __restrict__ imp) {
    __shared__ float row[2048];
    __shared__ float red[4][16];
    const int m = blockIdx.x, t = threadIdx.x;
    for (int i = t; i < 2048; i += 256) {
        float v = hs[(long)m * 2048 + i];
        row[i] = v;
        HSb[(long)m * 2048 + i] = f2bf(v);
    }
    __syncthreads();
    float p[16];
#pragma unroll
    for (int h = 0; h < 16; h++) p[h] = 0.f;
    for (int i = t * 8; i < t * 8 + 8; i++) {
        const float v = row[i];
        const float* u = U + i * 16;
#pragma unroll
        for (int h = 0; h < 16; h++) p[h] += v * u[h];
    }
#pragma unroll
    for (int off = 32; off; off >>= 1)
#pragma unroll
        for (int h = 0; h < 16; h++) p[h] += __shfl_down(p[h], off);
    if ((t & 63) == 0)
#pragma unroll
        for (int h = 0; h < 16; h++) red[t >> 6][h] = p[h];
    __syncthreads();
    if (t < 16)
        imp[(long)t * 2048 + m] = red[0][t] + red[1][t] + red[2][t] + red[3][t];
}

// ---------------------------------------------------------------------------
// exact top-256 per head, emitting inverse map jpos[h][token] = j (or -1).
// One wave per head; register-resident ballot binary search; strictly-greater
// elements ranked first (stable r asc, lane asc), then threshold ties
// lowest-index-first until 256.
// ---------------------------------------------------------------------------
__global__ __launch_bounds__(64) void topk_jpos(const float* __restrict__ imp,
                                                int* __restrict__ jpos) {
    const int h = blockIdx.x;
    const int lane = threadIdx.x;
    unsigned u[32];
#pragma unroll
    for (int r = 0; r < 32; r++) {
        unsigned x = __float_as_uint(imp[(long)h * 2048 + r * 64 + lane]);
        u[r] = (x & 0x80000000u) ? ~x : (x | 0x80000000u);
    }
    unsigned cur = 0;
    for (int b = 31; b >= 0; b--) {
        const unsigned cand = cur | (1u << b);
        int tot = 0;
#pragma unroll
        for (int r = 0; r < 32; r++)
            tot += (int)__popcll(__ballot(u[r] >= cand));
        if (tot >= 256) cur = cand;
    }
    const unsigned long long below = (1ull << lane) - 1ull;
    int pos[32];
    int base = 0;
#pragma unroll
    for (int r = 0; r < 32; r++) {
        const bool q = u[r] > cur;
        const unsigned long long m = __ballot(q);
        pos[r] = q ? base + (int)__popcll(m & below) : -1;
        base += (int)__popcll(m);
    }
    // ties at threshold continue from the strict count
#pragma unroll
    for (int r = 0; r < 32; r++) {
        const bool q = (u[r] == cur);
        const unsigned long long m = __ballot(q);
        if (q) {
            const int p = base + (int)__popcll(m & below);
            pos[r] = (p < 256) ? p : -1;
        }
        base += (int)__popcll(m);
    }
#pragma unroll
    for (int r = 0; r < 32; r++)
        jpos[h * 2048 + r * 64 + lane] = pos[r];
}

// ---------------------------------------------------------------------------
extern "C" void kernel_launch(void* const* d_in, const int* in_sizes, int n_in,
                              void* d_out, int out_size, void* d_ws, size_t ws_size,
                              hipStream_t stream)
{
    const float* hs = (const float*)d_in[0];
    const float* Wq = (const float*)d_in[1];
    const float* bq = (const float*)d_in[2];
    const float* Wk = (const float*)d_in[3];
    const float* bk = (const float*)d_in[4];
    const float* Wv = (const float*)d_in[5];
    const float* bv = (const float*)d_in[6];
    const float* Wo = (const float*)d_in[7];
    const float* bo = (const float*)d_in[8];

    char* ws = (char*)d_ws;
    size_t off = 0;
    auto alloc = [&](size_t b) -> void* {
        void* p = ws + off;
        off = (off + b + 255) & ~(size_t)255;
        return p;
    };
    unsigned short* HSb   = (unsigned short*)alloc(8388608);     // 2048x2048 bf16
    unsigned short* WT4   = (unsigned short*)alloc(4 * 8388608); // WqT|WkT|WvT|WoT
    unsigned short* Qb    = (unsigned short*)alloc(8388608);     // Q [2048][2048]
    unsigned short* Att   = (unsigned short*)alloc(8388608);
    unsigned short* Ksel  = (unsigned short*)alloc(1048576);     // [16][256][128]
    unsigned short* VselT = (unsigned short*)alloc(1048576);     // [16][128][256]
    float* Opart = (float*)alloc(2 * 16777216);                  // [2][2048][2048] fp32
    double* part  = (double*)alloc(1048576);                     // [64][2048]
    double* partq = (double*)alloc(1048576);                     // [64][2048]
    float* qbar  = (float*)alloc(8192);
    float* U     = (float*)alloc(131072);                        // [2048][16]
    float* imp   = (float*)alloc(131072);                        // [16][2048]
    int*   jpos  = (int*)alloc(131072);                          // [16][2048]

    if (off > ws_size) {
        fill_kernel<<<4096, 256, 0, stream>>>((float*)d_out, 12345.0f, (long)out_size);
        return;
    }

    unsigned short* WoT = WT4 + 3 * 4194304;

    // 1. weight transposes (64x64 tiles) + colsum partials (fused)
    prep_kernel<<<4608, 256, 0, stream>>>(Ptr4{{Wq, Wk, Wv, Wo}}, WT4, hs, part);

    // 2-5. ranking chain (exact, deterministic)
    mean_qsum_part<<<dim3(8, 64), 256, 0, stream>>>(part, Wq, partq);
    qsum_fin<<<32, 64, 0, stream>>>(partq, bq, qbar);
    u_kernel<<<2048, 256, 0, stream>>>(Wk, qbar, U);
    cast_imp_kernel<<<2048, 256, 0, stream>>>(hs, U, HSb, imp);

    // 6. top-256 per head -> inverse map jpos[h][token]
    topk_jpos<<<16, 64, 0, stream>>>(imp, jpos);

    // 7. QKV batched GEMM; K/V epilogues scatter selected rows only
    gemm_bf16<true><<<dim3(16, 16, 3), 256, 0, stream>>>(
        HSb, 2048, 0, WT4, 2048, 4194304, Qb, 2048, 0,
        Bias3{bq, bk, bv}, 2048, jpos, Ksel, VselT);

    // 8. fused attention: S, softmax, PV  (64-query tiles)
    attn_kernel<<<dim3(32, 16), 256, 0, stream>>>(Qb, Ksel, VselT, Att);

    // 9. O GEMM split-K=2: fp32 partials (K chunks of 1024)
    gemm_bf16<false><<<dim3(16, 16, 2), 256, 0, stream>>>(
        Att, 2048, 1024, WoT, 2048, 1024, Opart, 2048, 4194304,
        Bias3{nullptr, nullptr, nullptr}, 1024, nullptr, nullptr, nullptr);

    // 10. out = Opart0 + Opart1 + bo
    oreduce<<<4096, 256, 0, stream>>>(Opart, bo, (float*)d_out);
}